// Round 1
// baseline (673.740 us; speedup 1.0000x reference)
//
#include <hip/hip_runtime.h>

#define NN 12288
#define DD 128

// zero_out grid: ZGRID*256 threads, each storing ZITER float4s.
// NN*NN/4 = 37,748,736 float4s = ZGRID(4096) * 256 * ZITER(36) exactly.
#define ZGRID 4096
#define ZITER 36

typedef float v4f __attribute__((ext_vector_type(4)));

// ---------------------------------------------------------------------------
// Kernel 1: pure streaming zero-fill of the whole 604 MB output.
// Clone of the rocclr fill pattern (measured 6.37 TB/s, FETCH~0 on this exact
// buffer): no loads, no branches, per-wave 1 KB contiguous store bursts,
// grid-strided so every store instruction covers a contiguous 16 MB segment.
// ---------------------------------------------------------------------------
__global__ __launch_bounds__(256) void zero_out(float* __restrict__ out)
{
    v4f* __restrict__ o4 = reinterpret_cast<v4f*>(out);
    const v4f z = {0.f, 0.f, 0.f, 0.f};
    const size_t base = (size_t)blockIdx.x * 256 + threadIdx.x;
    #pragma unroll
    for (int k = 0; k < ZITER; ++k)
        o4[base + (size_t)k * ((size_t)ZGRID * 256)] = z;
}

// ---------------------------------------------------------------------------
// Kernel 2: overwrite only the same-graph band chunks of each row with the
// masked dot products (plus the in-band zeros). Runs after zero_out on the
// same stream, so the double-write is race-free (12.6 MB, ~2 us of BW).
// Dot product keeps the exact in-order fmaf chain of the previous kernel
// so the bit-exact absmax=0.0 match is preserved.
// ---------------------------------------------------------------------------
__global__ __launch_bounds__(128) void band_fill(
    const float* __restrict__ z1, const float* __restrict__ z2,
    const int* __restrict__ cls, const int* __restrict__ batch,
    float* __restrict__ out)
{
    const int i = blockIdx.x;
    const int cls_i = cls[i];
    if (cls_i >= 24) return;                 // excluded class: row stays zero

    // same-graph band [lo, hi): batch[] sorted -> binary search (block-uniform)
    const int batch_i = batch[i];
    int l = 0, r = NN;
    while (l < r) { const int m = (l + r) >> 1; if (batch[m] <  batch_i) l = m + 1; else r = m; }
    const int lo = l;
    r = NN;
    while (l < r) { const int m = (l + r) >> 1; if (batch[m] <= batch_i) l = m + 1; else r = m; }
    const int hi = l;

    const v4f* __restrict__ za  = reinterpret_cast<const v4f*>(z1 + (size_t)i * DD);
    v4f* __restrict__ orow      = reinterpret_cast<v4f*>(out + (size_t)i * NN);

    const int c0 = lo >> 2;                  // first float4 chunk touching the band
    const int c1 = (hi - 1) >> 2;            // last  float4 chunk touching the band

    for (int c = c0 + (int)threadIdx.x; c <= c1; c += 128) {
        float vv[4] = {0.f, 0.f, 0.f, 0.f};
        #pragma unroll
        for (int u = 0; u < 4; ++u) {
            const int j = (c << 2) | u;
            if (j >= lo && j < hi && j != i && cls[j] == cls_i) {
                const v4f* __restrict__ zb =
                    reinterpret_cast<const v4f*>(z2 + (size_t)j * DD);
                float s = 0.f;
                #pragma unroll
                for (int d = 0; d < DD / 4; ++d) {
                    const v4f a = za[d];
                    const v4f b = zb[d];
                    s = fmaf(a.x, b.x, s);
                    s = fmaf(a.y, b.y, s);
                    s = fmaf(a.z, b.z, s);
                    s = fmaf(a.w, b.w, s);
                }
                vv[u] = s;
            }
        }
        const v4f v = {vv[0], vv[1], vv[2], vv[3]};
        orow[c] = v;
    }
}

extern "C" void kernel_launch(void* const* d_in, const int* in_sizes, int n_in,
                              void* d_out, int out_size, void* d_ws, size_t ws_size,
                              hipStream_t stream) {
    const float* z1    = (const float*)d_in[0];
    const float* z2    = (const float*)d_in[1];
    const int*   cls   = (const int*)d_in[2];
    const int*   batch = (const int*)d_in[3];
    float*       out   = (float*)d_out;

    zero_out<<<ZGRID, 256, 0, stream>>>(out);
    band_fill<<<NN, 128, 0, stream>>>(z1, z2, cls, batch, out);
}

// Round 2
// 646.584 us; speedup vs baseline: 1.0420x; 1.0420x over previous
//
#include <hip/hip_runtime.h>

#define NN 12288
#define DD 128

typedef float v4f __attribute__((ext_vector_type(4)));

// One block per output row. 256 threads; thread t owns float4 chunks
// {t + 256*k : k=0..11}.
//
// Key change vs R0 (644us) and R1 (674us):
//   - ALL 12 chunks are zero-stored unconditionally BEFORE any load-dependent
//     work. The store stream starts at cycle ~0 of every block instead of
//     waiting on the ~28-deep dependent binary-search chain (R0 predicated
//     every store on lo/hi; that gated ~96us of HBM traffic behind ~4000
//     cycles of latency per block).
//   - Band chunks are then OVERWRITTEN by the same lane that zeroed them.
//     A single s_waitcnt vmcnt(0) before the first overwrite orders the
//     same-address double-write; by then the zero stores have long completed.
//   - Single kernel: no inter-kernel drain bubble (R1's mistake).
//   - Bijective XCD swizzle (12288%8==0): same-graph rows colocate on one
//     XCD so the z2/cls band reads hit that XCD's L2.
__global__ __launch_bounds__(256, 2) void segdec_fused(
    const float* __restrict__ z1, const float* __restrict__ z2,
    const int* __restrict__ cls, const int* __restrict__ batch,
    float* __restrict__ out)
{
    const int bid = (int)blockIdx.x;
    const int i   = (bid & 7) * (NN >> 3) + (bid >> 3);   // XCD-chunked remap
    const int tid = threadIdx.x;

    v4f* __restrict__ orow = reinterpret_cast<v4f*>(out + (size_t)i * NN);
    const v4f zero4 = {0.f, 0.f, 0.f, 0.f};

    // ---- Pass A: unconditional zero stream, no loads ahead of it ----------
    #pragma unroll
    for (int k = 0; k < 12; ++k)
        __builtin_nontemporal_store(zero4, &orow[tid + (k << 8)]);

    // ---- Row metadata (latency overlaps the in-flight stores) ------------
    const int cls_i = cls[i];
    if (cls_i >= 24) return;                 // excluded class: row stays zero

    const int batch_i = batch[i];
    int lo, hi;
    {
        int l = 0, r = NN;
        while (l < r) { const int m = (l + r) >> 1; if (batch[m] <  batch_i) l = m + 1; else r = m; }
        lo = l;
        r = NN;
        while (l < r) { const int m = (l + r) >> 1; if (batch[m] <= batch_i) l = m + 1; else r = m; }
        hi = l;
    }

    // ---- Band membership mask for this thread's chunks --------------------
    unsigned band_mask = 0u;
    #pragma unroll
    for (int k = 0; k < 12; ++k) {
        const int c0 = (tid + (k << 8)) << 2;
        if (c0 < hi && c0 + 4 > lo) band_mask |= (1u << k);
    }

    // ---- Pass B: overwrite band chunks (same lane as the zero store) ------
    if (band_mask) {
        // Order the same-address double-write. The search above took far
        // longer than store completion, so this is ~free.
        asm volatile("s_waitcnt vmcnt(0)" ::: "memory");

        const v4f* __restrict__ za = reinterpret_cast<const v4f*>(z1 + (size_t)i * DD);
        while (band_mask) {
            const int k = __builtin_ctz(band_mask);
            band_mask &= band_mask - 1;
            const int f4 = tid + (k << 8);
            const int c0 = f4 << 2;
            float vv[4] = {0.f, 0.f, 0.f, 0.f};
            #pragma unroll
            for (int u = 0; u < 4; ++u) {
                const int j = c0 + u;
                if (j >= lo && j < hi && j != i && cls[j] == cls_i) {
                    const v4f* __restrict__ zb =
                        reinterpret_cast<const v4f*>(z2 + (size_t)j * DD);
                    float s = 0.f;
                    #pragma unroll
                    for (int d = 0; d < DD / 4; ++d) {
                        const v4f a = za[d];
                        const v4f b = zb[d];
                        s = fmaf(a.x, b.x, s);
                        s = fmaf(a.y, b.y, s);
                        s = fmaf(a.z, b.z, s);
                        s = fmaf(a.w, b.w, s);
                    }
                    vv[u] = s;
                }
            }
            const v4f v = {vv[0], vv[1], vv[2], vv[3]};
            __builtin_nontemporal_store(v, &orow[f4]);
        }
    }
}

extern "C" void kernel_launch(void* const* d_in, const int* in_sizes, int n_in,
                              void* d_out, int out_size, void* d_ws, size_t ws_size,
                              hipStream_t stream) {
    const float* z1    = (const float*)d_in[0];
    const float* z2    = (const float*)d_in[1];
    const int*   cls   = (const int*)d_in[2];
    const int*   batch = (const int*)d_in[3];
    float*       out   = (float*)d_out;

    segdec_fused<<<NN, 256, 0, stream>>>(z1, z2, cls, batch, out);
}